// Round 7
// baseline (366.107 us; speedup 1.0000x reference)
//
#include <hip/hip_runtime.h>
#include <math.h>

typedef float v2f __attribute__((ext_vector_type(2)));

namespace {
constexpr int B = 2;
constexpr int N = 16384;
constexpr int M = 4096;
constexpr int GD = 16;                 // grid cells per axis
constexpr int NC = GD * GD * GD;       // 4096 cells
constexpr float GORG = -4.0f;          // grid origin
constexpr float GSCL = 2.0f;           // cells per unit (cell width 0.5)
constexpr int CAP = 96;                // per-query hit capacity (E[hits]~12-19)
constexpr int KE = CAP / 16;           // entries per lane in Phase C
constexpr int QPB2 = 16;               // queries per block (4 waves x 4 groups)
// workspace layout (bytes)
constexpr size_t OFF_WS4 = 0;                                  // float4[B][M] sorted pts (w=|s|^2)
constexpr size_t OFF_IDX = OFF_WS4 + (size_t)B * M * 16;       // u16[B][M] orig index
constexpr size_t OFF_CS  = OFF_IDX + (size_t)B * M * 2;        // u32[B][NC+1] cellStart
constexpr size_t OFF_QP  = OFF_CS + (size_t)B * (NC + 1) * 4;  // u16[B][N] sorted->orig query perm
constexpr size_t WS_NEEDED = OFF_QP + (size_t)B * N * 2;       // ~246 KB
}

// Shifted squared distance: d2of = |s|^2 - 2 p.s  (= true d2 - |p|^2).
// Bit-identical to the R0-R5 validated helper; comparisons are within-query.
__device__ __forceinline__ float d2of(const float4 s, float m2x, float m2y, float m2z) {
  return fmaf(m2z, s.z, fmaf(m2y, s.y, fmaf(m2x, s.x, s.w)));
}

template <int CTRL>
__device__ __forceinline__ float dpp_mov_f(float x) {
  int xi = __float_as_int(x);
  int r = __builtin_amdgcn_update_dpp(xi, xi, CTRL, 0xF, 0xF, false);
  return __int_as_float(r);
}

// ===================== build: bin+sort spoints, sort queries by cell ========
// one block per batch; LDS histogram + Hillis-Steele prefix + scatter.
__global__ __launch_bounds__(1024) void voro_build(
    const float* __restrict__ points,    // [B,N,3] queries
    const float* __restrict__ spoints,   // [B,M,3] candidates
    char* __restrict__ ws)
{
  const int b = blockIdx.x;
  const int tid = (int)threadIdx.x;
  __shared__ unsigned int hist[NC];
  __shared__ unsigned int scn[1024];

  float4* __restrict__ ws4g = (float4*)(ws + OFF_WS4);
  unsigned short* __restrict__ idxg = (unsigned short*)(ws + OFF_IDX);
  unsigned int* __restrict__ csg = (unsigned int*)(ws + OFF_CS);
  unsigned short* __restrict__ qpg = (unsigned short*)(ws + OFF_QP);

  auto cellof = [](float x, float y, float z) {
    int cx = (int)floorf((x - GORG) * GSCL); cx = cx < 0 ? 0 : (cx > GD - 1 ? GD - 1 : cx);
    int cy = (int)floorf((y - GORG) * GSCL); cy = cy < 0 ? 0 : (cy > GD - 1 ? GD - 1 : cy);
    int cz = (int)floorf((z - GORG) * GSCL); cz = cz < 0 ? 0 : (cz > GD - 1 ? GD - 1 : cz);
    return (cz * GD + cy) * GD + cx;
  };
  // exclusive prefix of hist[NC] in place (chunk-of-4 per thread + block scan)
  auto prefix = [&]() {
    const int c0 = tid * 4;
    unsigned v0 = hist[c0], v1 = hist[c0 + 1], v2 = hist[c0 + 2], v3 = hist[c0 + 3];
    unsigned s = v0 + v1 + v2 + v3;
    scn[tid] = s;
    __syncthreads();
    for (int off = 1; off < 1024; off <<= 1) {
      unsigned t = scn[tid];
      unsigned u = (tid >= off) ? scn[tid - off] : 0u;
      __syncthreads();
      scn[tid] = t + u;
      __syncthreads();
    }
    unsigned base = scn[tid] - s;
    hist[c0] = base; hist[c0 + 1] = base + v0;
    hist[c0 + 2] = base + v0 + v1; hist[c0 + 3] = base + v0 + v1 + v2;
    __syncthreads();
  };

  // ---- points ----
  for (int i = 0; i < 4; ++i) hist[tid * 4 + i] = 0u;
  __syncthreads();
  const float* sp = spoints + (size_t)b * M * 3;
  for (int k = 0; k < 4; ++k) {
    int j = tid + (k << 10);
    atomicAdd(&hist[cellof(sp[j * 3], sp[j * 3 + 1], sp[j * 3 + 2])], 1u);
  }
  __syncthreads();
  prefix();
  for (int i = 0; i < 4; ++i) csg[(size_t)b * (NC + 1) + tid * 4 + i] = hist[tid * 4 + i];
  if (tid == 0) csg[(size_t)b * (NC + 1) + NC] = (unsigned)M;
  __syncthreads();
  for (int k = 0; k < 4; ++k) {
    int j = tid + (k << 10);
    float x = sp[j * 3], y = sp[j * 3 + 1], z = sp[j * 3 + 2];
    unsigned pos = atomicAdd(&hist[cellof(x, y, z)], 1u);
    ws4g[(size_t)b * M + pos] = make_float4(x, y, z, x * x + y * y + z * z);
    idxg[(size_t)b * M + pos] = (unsigned short)j;
  }
  __syncthreads();

  // ---- queries (permutation only) ----
  for (int i = 0; i < 4; ++i) hist[tid * 4 + i] = 0u;
  __syncthreads();
  const float* qq = points + (size_t)b * N * 3;
  for (int k = 0; k < 16; ++k) {
    int j = tid + (k << 10);
    atomicAdd(&hist[cellof(qq[j * 3], qq[j * 3 + 1], qq[j * 3 + 2])], 1u);
  }
  __syncthreads();
  prefix();
  for (int k = 0; k < 16; ++k) {
    int j = tid + (k << 10);
    unsigned pos = atomicAdd(&hist[cellof(qq[j * 3], qq[j * 3 + 1], qq[j * 3 + 2])], 1u);
    qpg[(size_t)b * N + pos] = (unsigned short)j;
  }
}

// ===================== query: exact kNN via expanding shells ================
// WAVE-UNIFORM control flow (R6 lesson): shell expansion decided by __any
// across the wave; rows predicated to zero-length runs instead of `continue`;
// every ballot/shfl executes with the full wave converged.
__global__ __launch_bounds__(256, 4) void voro_query(
    const float* __restrict__ points,
    const char* __restrict__ ws,
    float* __restrict__ out)
{
  const int tid = (int)threadIdx.x;
  const int wl = tid & 63, g = tid >> 6;
  const int gr = wl >> 4, gl = wl & 15, grbase = wl & 48;
  const int b = (int)blockIdx.x >> 10, tile = (int)blockIdx.x & 1023;
  const unsigned long long gmask = 0xFFFFull << (gr << 4);
  const unsigned long long lanelt = (1ull << wl) - 1ull;

  const float4* __restrict__ ws4g = (const float4*)(ws + OFF_WS4);
  const unsigned short* __restrict__ idxg = (const unsigned short*)(ws + OFF_IDX);
  const unsigned int* __restrict__ csg = (const unsigned int*)(ws + OFF_CS);
  const unsigned short* __restrict__ qpg = (const unsigned short*)(ws + OFF_QP);

  __shared__ unsigned short buf[QPB2][CAP];
  unsigned short* bufq = buf[g * 4 + gr];

  const int qs = tile * QPB2 + g * 4 + gr;
  const int orig = (int)qpg[(size_t)b * N + qs];
  const float* qp_ = points + ((size_t)b * N + orig) * 3;
  const float px = qp_[0], py = qp_[1], pz = qp_[2];
  const float m2x = -2.0f * px, m2y = -2.0f * py, m2z = -2.0f * pz;
  const float pp = px * px + py * py + pz * pz;

  const float gx = (px - GORG) * GSCL, gy = (py - GORG) * GSCL, gz = (pz - GORG) * GSCL;
  int cx = (int)floorf(gx); cx = cx < 0 ? 0 : (cx > GD - 1 ? GD - 1 : cx);
  int cy = (int)floorf(gy); cy = cy < 0 ? 0 : (cy > GD - 1 ? GD - 1 : cy);
  int cz = (int)floorf(gz); cz = cz < 0 ? 0 : (cz > GD - 1 ? GD - 1 : cz);
  const float fx = gx - (float)cx, fy = gy - (float)cy, fz = gz - (float)cz;
  // min face distance in cell units (can be negative for clamped queries ->
  // smaller bound -> conservative extra scanning, still correct)
  const float mnf = fminf(fminf(fminf(fx, 1.0f - fx), fminf(fy, 1.0f - fy)),
                          fminf(fz, 1.0f - fz));

  const int wsbase = b * M;
  const int csbase = b * (NC + 1);

  float lmin = INFINITY;
  int cnt = 0, cntB = 0, hcnt = 0;
  float theta = INFINITY;

  // ---- run processors: global candidate ordinal r -> lane r&15 (round-robin
  // across runs; with cnt>=11 this guarantees >=11 non-empty lanes).
  auto runA = [&](unsigned stu, unsigned enu) {
    int st = (int)stu, en = (int)enu, len = en - st;
    int off = (gl - cnt) & 15;
    int T = (len + 15) >> 4;
    for (int t = 0; t < T; ++t) {
      int j = st + off + (t << 4);
      bool valid = j < en;
      int jc = valid ? j : st;
      float4 sv = ws4g[wsbase + jc];
      float d2 = d2of(sv, m2x, m2y, m2z);
      if (valid) lmin = fminf(lmin, d2);
    }
    cnt += len;
  };
  auto runB = [&](unsigned stu, unsigned enu) {
    int st = (int)stu, en = (int)enu, len = en - st;
    int off = (gl - cntB) & 15;     // replay of runA's cursor
    int T = (len + 15) >> 4;
    for (int t = 0; t < T; ++t) {
      int j = st + off + (t << 4);
      bool valid = j < en;
      int jc = valid ? j : st;
      float4 sv = ws4g[wsbase + jc];
      float d2 = d2of(sv, m2x, m2y, m2z);
      bool hit = valid && (d2 <= theta);
      unsigned long long gb = __ballot(hit) & gmask;
      if (hit) {
        int pos = hcnt + (int)__popcll(gb & lanelt);
        if (pos < CAP) bufq[pos] = (unsigned short)jc;
      }
      hcnt += (int)__popcll(gb);
    }
    cntB += len;
  };
  // Predicated row: OOB rows/cells become zero-length runs (loads always use
  // clamped-valid addresses; validity gates only the VALUES). Corruption
  // clamps (st<=en<=M) make garbage cellStarts harmless.
  auto rowrun = [&](int nz, int ny, int x0, int x1, auto&& run) {
    bool ok = ((unsigned)nz < (unsigned)GD) && ((unsigned)ny < (unsigned)GD) &&
              (x0 >= 0) && (x1 < GD) && (x0 <= x1);
    int nzc = nz < 0 ? 0 : (nz > GD - 1 ? GD - 1 : nz);
    int nyc = ny < 0 ? 0 : (ny > GD - 1 ? GD - 1 : ny);
    int x0c = x0 < 0 ? 0 : (x0 > GD - 1 ? GD - 1 : x0);
    int x1c = x1 < 0 ? 0 : (x1 > GD - 1 ? GD - 1 : x1);
    int rb = csbase + (nzc * GD + nyc) * GD;
    unsigned st = csg[rb + x0c], en = csg[rb + x1c + 1];
    ok = ok && (st <= en) && (en <= (unsigned)M);
    run(ok ? st : 0u, ok ? en : 0u);
  };
  auto cube = [&](auto&& run) {
    for (int dz = -1; dz <= 1; ++dz)
      for (int dy = -1; dy <= 1; ++dy)
        rowrun(cz + dz, cy + dy, cx > 0 ? cx - 1 : 0,
               cx < GD - 1 ? cx + 1 : GD - 1, run);
  };
  auto shell = [&](int s, auto&& run) {   // Chebyshev shell s (>=2), no dupes
    for (int dz = -s; dz <= s; ++dz) {
      int adz = dz < 0 ? -dz : dz;
      for (int dy = -s; dy <= s; ++dy) {
        int ady = dy < 0 ? -dy : dy;
        if (adz == s || ady == s) {       // wave-uniform branch (s,dz,dy uniform)
          int x0 = cx - s; x0 = x0 < 0 ? 0 : x0;
          int x1 = cx + s; x1 = x1 > GD - 1 ? GD - 1 : x1;
          rowrun(cz + dz, cy + dy, x0, x1, run);
        } else {
          rowrun(cz + dz, cy + dy, cx - s, cx - s, run);
          rowrun(cz + dz, cy + dy, cx + s, cx + s, run);
        }
      }
    }
  };
  // 11th smallest of the 16 lane minima (group bitonic, j<=8 in-group).
  // INF for empty lanes sorts high: with <11 populated lanes theta=INF,
  // which keeps `need` true below — no cnt>=11 conditional required.
  auto compute_theta = [&]() -> float {
    float x = lmin;
#pragma unroll
    for (int k = 2; k <= 16; k <<= 1) {
#pragma unroll
      for (int j = k >> 1; j > 0; j >>= 1) {
        float o = __shfl_xor(x, j);
        bool up = (gl & k) == 0;
        bool lower = (gl & j) == 0;
        x = (lower == up) ? fminf(x, o) : fmaxf(x, o);
      }
    }
    return __shfl(x, grbase + 10);
  };

  // ---- Pass A: cube then wave-uniform bounded shell expansion
  cube(runA);
  theta = compute_theta();
  int s = 2;
  for (; s <= GD - 1; ++s) {
    float smc = (float)(s - 1) + mnf;           // lower bound to shell s (cells)
    smc = fmaxf(smc, 0.0f) * 0.5f;              // -> real units
    float tht = theta + pp;                     // unshift to true d2 (INF-safe)
    bool need = !(smc * smc > tht * 1.0001f + 1e-6f);
    if (!__any(need)) break;                    // wave-uniform decision
    shell(s, runA);
    theta = compute_theta();
  }
  const int s_stop = s;                         // wave-uniform

  // ---- Pass B: deterministic replay, collect all d2 <= theta (>=11: the 11
  // smallest lane-minima are distinct candidates <= theta)
  cube(runB);
  for (int ss = 2; ss < s_stop; ++ss) shell(ss, runB);

  // ---- Phase C: exact lex (d2, origIdx) rank (= stable top_k) + epilogue
  int c = hcnt < CAP ? hcnt : CAP;
  int mc = c;
  { int o = __shfl_xor(mc, 16); mc = mc > o ? mc : o;
    o = __shfl_xor(mc, 32); mc = mc > o ? mc : o; }   // wave-uniform max

  float d2e[KE]; int ide[KE], pose[KE], rank[KE];
#pragma unroll
  for (int k = 0; k < KE; ++k) {
    int e = gl + (k << 4);
    bool vv = e < c;
    int pos = vv ? (int)bufq[e] : 0;
    float4 sv = ws4g[wsbase + pos];
    d2e[k] = vv ? d2of(sv, m2x, m2y, m2z) : INFINITY;
    ide[k] = vv ? (int)idxg[wsbase + pos] : 0x7fffffff;
    pose[k] = pos;
    rank[k] = 0;
  }
#pragma unroll
  for (int kk = 0; kk < KE; ++kk) {
    if ((kk << 4) >= mc) break;                 // wave-uniform
    for (int f2 = 0; f2 < 16; ++f2) {
      int f = (kk << 4) + f2;
      if (f >= mc) break;                       // wave-uniform
      float df = __shfl(d2e[kk], grbase + f2);
      int jf = __shfl(ide[kk], grbase + f2);
#pragma unroll
      for (int k = 0; k < KE; ++k)
        rank[k] += ((df < d2e[k]) || (df == d2e[k] && jf < ide[k])) ? 1 : 0;
    }
  }
  // center = rank 0 (exists, unique by lex key)
  int cpos = 0;
#pragma unroll
  for (int k = 0; k < KE; ++k) {
    unsigned long long bk = __ballot((gl + (k << 4) < c) && rank[k] == 0) & gmask;
    if (bk) {
      int sl = (int)__builtin_ctzll(bk);
      cpos = __shfl(pose[k], sl);
    }
  }
  float4 cc = ws4g[wsbase + cpos];
  float vx = px - cc.x, vy = py - cc.y, vz = pz - cc.z;
  float best = INFINITY;
#pragma unroll
  for (int k = 0; k < KE; ++k) {
    bool isedge = (gl + (k << 4) < c) && (rank[k] >= 1) && (rank[k] <= 10);
    float4 sv = ws4g[wsbase + pose[k]];
    float ex = sv.x - cc.x, ey = sv.y - cc.y, ez = sv.z - cc.z;
    float el2 = ex * ex; el2 = fmaf(ey, ey, el2); el2 = fmaf(ez, ez, el2);
    float dv = vx * ex; dv = fmaf(vy, ey, dv); dv = fmaf(vz, ez, dv);
    float tt = fmaf(-0.5f, el2, dv);
    float sq = tt * tt * __builtin_amdgcn_rcpf(el2);
    best = fminf(best, isedge ? sq : INFINITY);
  }
  best = fminf(best, dpp_mov_f<0x111>(best));   // row_shr:1
  best = fminf(best, dpp_mov_f<0x112>(best));   // row_shr:2
  best = fminf(best, dpp_mov_f<0x114>(best));   // row_shr:4
  best = fminf(best, dpp_mov_f<0x118>(best));   // row_shr:8 -> lane15 = group min
  if (gl == 15) out[(size_t)b * N + orig] = best;
}

// ===================== fallback: R4-validated brute kernel (84.2us) =========
namespace br {
constexpr int TQ = 64;
constexpr int BLOCK = 1024;
constexpr int Q = 4;
constexpr int GROUPS = BLOCK / TQ;
constexpr int QPB = GROUPS * Q;
constexpr int NB = 4;
constexpr int CAP = 48;
constexpr int CAPW = 256;

struct __attribute__((aligned(16))) S2 { v2f xy; v2f zw; };

__device__ __forceinline__ v2f d2pair(S2 s, v2f m2x, v2f m2y, v2f m2z) {
  v2f acc;
  asm("v_pk_fma_f32 %0, %1, %2, %3 op_sel:[0,0,1] op_sel_hi:[0,1,1]"
      : "=v"(acc) : "v"(s.xy), "v"(m2x), "v"(s.zw));
  asm("v_pk_fma_f32 %0, %1, %2, %0 op_sel:[1,0,0] op_sel_hi:[1,1,1]"
      : "+v"(acc) : "v"(s.xy), "v"(m2y));
  asm("v_pk_fma_f32 %0, %1, %2, %0 op_sel:[0,0,0] op_sel_hi:[0,1,1]"
      : "+v"(acc) : "v"(s.zw), "v"(m2z));
  return acc;
}

__global__ __launch_bounds__(BLOCK, 8) void voroloss_kernel(
    const float* __restrict__ points,
    const float* __restrict__ spoints,
    float* __restrict__ out)
{
  __shared__ float4 s4[M];
  __shared__ unsigned short wl_lds[GROUPS][CAPW];
  __shared__ __align__(16) unsigned short buf[QPB][CAP];

  const int blocks_per_batch = N / QPB;
  const int b = blockIdx.x / blocks_per_batch;
  const int tile = blockIdx.x % blocks_per_batch;
  const int tid = (int)threadIdx.x;
  const int wl = tid & 63;
  const int g = tid >> 6;

  const float* sp = spoints + (size_t)b * M * 3;
  for (int j = tid; j < M; j += BLOCK) {
    float x = sp[j * 3 + 0], y = sp[j * 3 + 1], z = sp[j * 3 + 2];
    s4[j] = make_float4(x, y, z, x * x + y * y + z * z);
  }

  float m2x[Q], m2y[Q], m2z[Q];
#pragma unroll
  for (int q = 0; q < Q; ++q) {
    int n = tile * QPB + q * GROUPS + g;
    m2x[q] = -2.0f * points[((size_t)b * N + n) * 3 + 0];
    m2y[q] = -2.0f * points[((size_t)b * N + n) * 3 + 1];
    m2z[q] = -2.0f * points[((size_t)b * N + n) * 3 + 2];
  }
  v2f bmx[2], bmy[2], bmz[2];
#pragma unroll
  for (int p = 0; p < 2; ++p) {
    bmx[p].x = m2x[2 * p]; bmx[p].y = m2x[2 * p + 1];
    bmy[p].x = m2y[2 * p]; bmy[p].y = m2y[2 * p + 1];
    bmz[p].x = m2z[2 * p]; bmz[p].y = m2z[2 * p + 1];
  }
  __syncthreads();
  const S2* s2 = (const S2*)s4;

  v2f bm2[2][NB];
#pragma unroll
  for (int p = 0; p < 2; ++p)
#pragma unroll
    for (int bi = 0; bi < NB; ++bi) { bm2[p][bi].x = INFINITY; bm2[p][bi].y = INFINITY; }

#pragma unroll
  for (int bi = 0; bi < NB; ++bi) {
#pragma unroll
    for (int hf = 0; hf < 4; ++hf) {
      S2 sv[4];
#pragma unroll
      for (int c = 0; c < 4; ++c) sv[c] = s2[(bi * 16 + hf * 4 + c) * TQ + wl];
#pragma unroll
      for (int p = 0; p < 2; ++p) {
        v2f a0 = d2pair(sv[0], bmx[p], bmy[p], bmz[p]);
        v2f a1 = d2pair(sv[1], bmx[p], bmy[p], bmz[p]);
        v2f a2 = d2pair(sv[2], bmx[p], bmy[p], bmz[p]);
        v2f a3 = d2pair(sv[3], bmx[p], bmy[p], bmz[p]);
        float tx = fminf(fminf(a0.x, a1.x), a2.x);
        bm2[p][bi].x = fminf(fminf(tx, a3.x), bm2[p][bi].x);
        float ty = fminf(fminf(a0.y, a1.y), a2.y);
        bm2[p][bi].y = fminf(fminf(ty, a3.y), bm2[p][bi].y);
      }
    }
  }
  float t0[Q];
#pragma unroll
  for (int p = 0; p < 2; ++p) {
    v2f m = bm2[p][0];
#pragma unroll
    for (int bi = 1; bi < NB; ++bi) {
      m.x = fminf(m.x, bm2[p][bi].x);
      m.y = fminf(m.y, bm2[p][bi].y);
    }
    t0[2 * p] = m.x; t0[2 * p + 1] = m.y;
  }

  const int h = wl & 31;
  bool km[15];
  {
    int st = 0;
#pragma unroll
    for (int k = 2; k <= 32; k <<= 1)
#pragma unroll
      for (int j = 16; j > 0; j >>= 1)
        if (j < k) {
          bool up = (h & k) == 0;
          bool lower = (h & j) == 0;
          km[st++] = (lower == up);
        }
  }
  float theta[Q];
#pragma unroll
  for (int qp = 0; qp < Q; qp += 2) {
    float a0 = fminf(t0[qp],     __shfl_xor(t0[qp],     32));
    float a1 = fminf(t0[qp + 1], __shfl_xor(t0[qp + 1], 32));
    float x = (wl < 32) ? a0 : a1;
    int st = 0;
#pragma unroll
    for (int k = 2; k <= 32; k <<= 1)
#pragma unroll
      for (int j = 16; j > 0; j >>= 1)
        if (j < k) {
          float o = __shfl_xor(x, j);
          x = km[st++] ? fminf(x, o) : fmaxf(x, o);
        }
    theta[qp]     = __shfl(x, 10, 64);
    theta[qp + 1] = __shfl(x, 42, 64);
  }

  int wcnt = 0;
#pragma unroll
  for (int bi = 0; bi < NB; ++bi) {
    bool hit = (bm2[0][bi].x <= theta[0]) || (bm2[0][bi].y <= theta[1]) ||
               (bm2[1][bi].x <= theta[2]) || (bm2[1][bi].y <= theta[3]);
    unsigned long long mask = __ballot(hit);
    if (mask != 0) {
      if (hit) {
        unsigned int lo = __builtin_amdgcn_mbcnt_lo((unsigned int)mask, 0u);
        unsigned int pr = __builtin_amdgcn_mbcnt_hi((unsigned int)(mask >> 32), lo);
        int pos = wcnt + (int)pr;
        if (pos < CAPW) wl_lds[g][pos] = (unsigned short)((bi << 6) | wl);
      }
      wcnt += (int)__popcll(mask);
    }
  }
  wcnt = wcnt < CAPW ? wcnt : CAPW;

  int cnt[Q];
#pragma unroll
  for (int q = 0; q < Q; ++q) cnt[q] = 0;

  for (int base = 0; base < wcnt; base += 64) {
    int ii = base + wl;
    bool val = ii < wcnt;
    int e = wl_lds[g][val ? ii : 0];
    int bi = e >> 6, src = e & 63;

    unsigned hm[Q] = {0u, 0u, 0u, 0u};
#pragma unroll
    for (int hf = 0; hf < 4; ++hf) {
      S2 sv[4];
#pragma unroll
      for (int c = 0; c < 4; ++c) sv[c] = s2[(bi * 16 + hf * 4 + c) * TQ + src];
#pragma unroll
      for (int p = 0; p < 2; ++p) {
#pragma unroll
        for (int c = 0; c < 4; ++c) {
          v2f acc = d2pair(sv[c], bmx[p], bmy[p], bmz[p]);
          unsigned bit = 1u << (hf * 4 + c);
          hm[2 * p]     |= (acc.x <= theta[2 * p])     ? bit : 0u;
          hm[2 * p + 1] |= (acc.y <= theta[2 * p + 1]) ? bit : 0u;
        }
      }
    }
    if (!val) { hm[0] = 0u; hm[1] = 0u; hm[2] = 0u; hm[3] = 0u; }

#pragma unroll
    for (int q = 0; q < Q; ++q) {
      const int qq = q * GROUPS + g;
      unsigned m = hm[q];
      unsigned long long bmk = __ballot(m != 0u);
      while (bmk) {
        bool have = m != 0u;
        int k = __ffs(m) - 1;
        unsigned int lo = __builtin_amdgcn_mbcnt_lo((unsigned int)bmk, 0u);
        unsigned int pr = __builtin_amdgcn_mbcnt_hi((unsigned int)(bmk >> 32), lo);
        int pos = cnt[q] + (int)pr;
        if (have && pos < CAP)
          buf[qq][pos] = (unsigned short)((bi * 16 + k) * TQ + src);
        cnt[q] += (int)__popcll(bmk);
        m &= m - 1u;
        bmk = __ballot(m != 0u);
      }
    }
  }

#pragma unroll
  for (int p = 0; p < 2; ++p) {
    const int qa = 2 * p, qb = 2 * p + 1;
    const int qqa = qa * GROUPS + g;
    const int qqb = qb * GROUPS + g;
    int ca = cnt[qa]; ca = ca < CAP ? ca : CAP;
    int cb = cnt[qb]; cb = cb < CAP ? cb : CAP;

    bool va = wl < ca, vb = wl < cb;
    int ida = (int)buf[qqa][va ? wl : 0];
    int idb = (int)buf[qqb][vb ? wl : 0];
    float4 sa = s4[ida];
    float4 sb = s4[idb];
    float d2a = va ? d2of(sa, m2x[qa], m2y[qa], m2z[qa]) : INFINITY;
    float d2b = vb ? d2of(sb, m2x[qb], m2y[qb], m2z[qb]) : INFINITY;
    ida = va ? ida : 0x7fffffff;
    idb = vb ? idb : 0x7fffffff;
    const int ba = __float_as_int(d2a);
    const int bb = __float_as_int(d2b);

    int cm = ca > cb ? ca : cb;
    int cm2 = (cm + 1) & ~1;
    int ranka = 0, rankb = 0;
    for (int f = 0; f < cm2; f += 2) {
#pragma unroll
      for (int u = 0; u < 2; ++u) {
        float dfa = __int_as_float(__builtin_amdgcn_readlane(ba, f + u));
        int jfa = __builtin_amdgcn_readlane(ida, f + u);
        float dfb = __int_as_float(__builtin_amdgcn_readlane(bb, f + u));
        int jfb = __builtin_amdgcn_readlane(idb, f + u);
        ranka += ((dfa < d2a) || (dfa == d2a && jfa < ida)) ? 1 : 0;
        rankb += ((dfb < d2b) || (dfb == d2b && jfb < idb)) ? 1 : 0;
      }
    }

#pragma unroll
    for (int hq = 0; hq < 2; ++hq) {
      const int q = hq == 0 ? qa : qb;
      const int rank = hq == 0 ? ranka : rankb;
      const bool v = hq == 0 ? va : vb;
      const int ide = hq == 0 ? ida : idb;
      const float4 se = hq == 0 ? sa : sb;

      unsigned long long cbm = __ballot(v && rank == 0);
      int cl = (int)__builtin_ctzll(cbm);
      int ci = __builtin_amdgcn_readlane(ide, cl);
      float4 cc = s4[ci];
      float px = -0.5f * m2x[q], py = -0.5f * m2y[q], pz = -0.5f * m2z[q];
      float vx = px - cc.x, vy = py - cc.y, vz = pz - cc.z;

      bool isedge = v && (rank >= 1) && (rank <= 10);
      float ex = se.x - cc.x, ey = se.y - cc.y, ez = se.z - cc.z;
      float el2 = ex * ex;
      el2 = fmaf(ey, ey, el2);
      el2 = fmaf(ez, ez, el2);
      float dv = vx * ex;
      dv = fmaf(vy, ey, dv);
      dv = fmaf(vz, ez, dv);
      float tt = fmaf(-0.5f, el2, dv);
      float sq = tt * tt * __builtin_amdgcn_rcpf(el2);
      float best = isedge ? sq : INFINITY;
#pragma unroll
      for (int lvl = 1; lvl <= 32; lvl <<= 1) {
        best = fminf(best, __shfl_xor(best, lvl));
      }
      if (wl == 0) out[(size_t)b * N + (tile * QPB + q * GROUPS + g)] = best;
    }
  }
}
}  // namespace br

extern "C" void kernel_launch(void* const* d_in, const int* in_sizes, int n_in,
                              void* d_out, int out_size, void* d_ws, size_t ws_size,
                              hipStream_t stream) {
  const float* points = (const float*)d_in[0];
  const float* spoints = (const float*)d_in[1];
  float* out = (float*)d_out;
  (void)in_sizes; (void)n_in; (void)out_size;
  if (d_ws != nullptr && ws_size >= WS_NEEDED) {
    char* ws = (char*)d_ws;
    voro_build<<<dim3(B), dim3(1024), 0, stream>>>(points, spoints, ws);
    voro_query<<<dim3(B * (N / QPB2)), dim3(256), 0, stream>>>(points, ws, out);
  } else {
    br::voroloss_kernel<<<dim3(B * (N / br::QPB)), dim3(br::BLOCK), 0, stream>>>(
        points, spoints, out);
  }
}